// Round 1
// baseline (91.896 us; speedup 1.0000x reference)
//
#include <hip/hip_runtime.h>

// DB4 reconstruction low-pass (float64 source, folded to f32 literals)
// dec_lo[j] = h[7-j]; dec_hi[j] = (-1)^(j+1) * h[j]
static constexpr float LO[8] = {
    -0.010597401784997278f,  0.032883011666982945f,  0.030841381835986965f,
    -0.18703481171888114f,  -0.02798376941698385f,   0.6308807679295904f,
     0.7148465705525415f,    0.23037781330885523f
};
static constexpr float HI[8] = {
    -0.23037781330885523f,   0.7148465705525415f,   -0.6308807679295904f,
    -0.02798376941698385f,   0.18703481171888114f,   0.030841381835986965f,
    -0.032883011666982945f, -0.010597401784997278f
};

// Forward DWT (periodic): a[i] = sum_j x[(2i+1-j)%N]*LO[j], d likewise with HI.
// Each thread produces two consecutive outputs (i0, i0+1) from one 10-wide
// window w[k] = x[(2*i0-6+k) % N], read as 5 aligned float2 (pair starts even,
// so no intra-pair wrap).
template<int N, bool WANT_A>
__device__ __forceinline__ void dwt_level(const float* __restrict__ x,
                                          float* __restrict__ a,
                                          float* __restrict__ d,
                                          int t)
{
    constexpr int M = N / 2;
    constexpr int ITERS = M / 512;   // (M/2) i0-values over 256 threads
    #pragma unroll
    for (int k = 0; k < ITERS; ++k) {
        const int i0 = 2 * (t + 256 * k);
        float w[10];
        #pragma unroll
        for (int c = 0; c < 5; ++c) {
            const int idx = (2 * i0 - 6 + 2 * c + N) & (N - 1);
            const float2 v = *(const float2*)(x + idx);
            w[2 * c] = v.x; w[2 * c + 1] = v.y;
        }
        float a0 = 0.f, a1 = 0.f, d0 = 0.f, d1 = 0.f;
        #pragma unroll
        for (int kk = 0; kk < 8; ++kk) {
            if (WANT_A) {
                a0 = fmaf(w[kk],     LO[7 - kk], a0);
                a1 = fmaf(w[kk + 2], LO[7 - kk], a1);
            }
            d0 = fmaf(w[kk],     HI[7 - kk], d0);
            d1 = fmaf(w[kk + 2], HI[7 - kk], d1);
        }
        if (WANT_A) *(float2*)(a + i0) = make_float2(a0, a1);
        *(float2*)(d + i0) = make_float2(d0, d1);
    }
}

// Inverse DWT (periodic), upsampling M -> 2M.
// out[2m]   = sum_q cA[(m+q)%M]*LO[2q+1] + cD[(m+q)%M]*HI[2q+1]
// out[2m+1] = sum_q cA[(m+q)%M]*LO[2q]   + cD[(m+q)%M]*HI[2q]
// Each thread takes m0 even, produces out[2m0..2m0+3] (float4), reading
// cA/cD[m0..m0+4] via 3 aligned float2 each.
template<int M, bool HAS_A>
__device__ __forceinline__ void idwt_level(const float* __restrict__ cA,
                                           const float* __restrict__ cD,
                                           float* __restrict__ out,
                                           int t)
{
    constexpr int ITERS = M / 512;
    #pragma unroll
    for (int k = 0; k < ITERS; ++k) {
        const int m0 = 2 * (t + 256 * k);
        float av[6], dv[6];
        #pragma unroll
        for (int c = 0; c < 3; ++c) {
            const int idx = (m0 + 2 * c) & (M - 1);
            if (HAS_A) {
                const float2 v = *(const float2*)(cA + idx);
                av[2 * c] = v.x; av[2 * c + 1] = v.y;
            }
            const float2 v2 = *(const float2*)(cD + idx);
            dv[2 * c] = v2.x; dv[2 * c + 1] = v2.y;
        }
        float s0 = 0.f, s1 = 0.f, s2 = 0.f, s3 = 0.f;
        #pragma unroll
        for (int q = 0; q < 4; ++q) {
            if (HAS_A) {
                s0 = fmaf(av[q],     LO[2 * q + 1], s0);
                s1 = fmaf(av[q],     LO[2 * q],     s1);
                s2 = fmaf(av[q + 1], LO[2 * q + 1], s2);
                s3 = fmaf(av[q + 1], LO[2 * q],     s3);
            }
            s0 = fmaf(dv[q],     HI[2 * q + 1], s0);
            s1 = fmaf(dv[q],     HI[2 * q],     s1);
            s2 = fmaf(dv[q + 1], HI[2 * q + 1], s2);
            s3 = fmaf(dv[q + 1], HI[2 * q],     s3);
        }
        *(float4*)(out + 2 * m0) = make_float4(s0, s1, s2, s3);
    }
}

// LDS arena layout (floats), 8192 * 4B = 32 KB:
//   X  [0:4096]      (dead after level 1)
//   A1 [4096:6144]   (dead after level 2)
//   D1 [6144:8192]   (live until final)
//   A2 [0:1024]      (aliases dead X; dead after level 3)
//   D2 [1024:2048]   (live until X1)
//   D3 [2048:2560]
//   X2 [2560:3584]
//   X1 [4096:6144]   (aliases dead A1)
__global__ __launch_bounds__(256)
void WaveletSeasonalDecomposer_43181601194295_kernel(const float* __restrict__ in,
                                                     float* __restrict__ seasonal,
                                                     float* __restrict__ residual)
{
    __shared__ __align__(16) float arena[8192];
    const int t = threadIdx.x;
    const int row = blockIdx.x;

    const float4* in4 = (const float4*)(in + (size_t)row * 4096);
    float4 xr[4];
    #pragma unroll
    for (int k = 0; k < 4; ++k) {
        const float4 v = in4[t + 256 * k];
        xr[k] = v;
        ((float4*)arena)[t + 256 * k] = v;
    }
    __syncthreads();

    dwt_level<4096, true >(arena,        arena + 4096, arena + 6144, t); // X  -> A1, D1
    __syncthreads();
    dwt_level<2048, true >(arena + 4096, arena,        arena + 1024, t); // A1 -> A2, D2
    __syncthreads();
    dwt_level<1024, false>(arena,        nullptr,      arena + 2048, t); // A2 -> D3 (a3 unused)
    __syncthreads();
    idwt_level<512,  false>(nullptr,       arena + 2048, arena + 2560, t); // 0,D3 -> X2
    __syncthreads();
    idwt_level<1024, true >(arena + 2560,  arena + 1024, arena + 4096, t); // X2,D2 -> X1
    __syncthreads();

    // Final level: X1,D1 -> seasonal (M=2048), fused with residual = x - seasonal.
    const float* X1 = arena + 4096;
    const float* D1 = arena + 6144;
    float4* outS4 = (float4*)(seasonal + (size_t)row * 4096);
    float4* outR4 = (float4*)(residual + (size_t)row * 4096);
    #pragma unroll
    for (int k = 0; k < 4; ++k) {
        const int m0 = 2 * (t + 256 * k);
        float av[6], dv[6];
        #pragma unroll
        for (int c = 0; c < 3; ++c) {
            const int idx = (m0 + 2 * c) & 2047;
            const float2 v  = *(const float2*)(X1 + idx);
            av[2 * c] = v.x;  av[2 * c + 1] = v.y;
            const float2 v2 = *(const float2*)(D1 + idx);
            dv[2 * c] = v2.x; dv[2 * c + 1] = v2.y;
        }
        float s0 = 0.f, s1 = 0.f, s2 = 0.f, s3 = 0.f;
        #pragma unroll
        for (int q = 0; q < 4; ++q) {
            s0 = fmaf(av[q],     LO[2 * q + 1], s0);
            s1 = fmaf(av[q],     LO[2 * q],     s1);
            s2 = fmaf(av[q + 1], LO[2 * q + 1], s2);
            s3 = fmaf(av[q + 1], LO[2 * q],     s3);
            s0 = fmaf(dv[q],     HI[2 * q + 1], s0);
            s1 = fmaf(dv[q],     HI[2 * q],     s1);
            s2 = fmaf(dv[q + 1], HI[2 * q + 1], s2);
            s3 = fmaf(dv[q + 1], HI[2 * q],     s3);
        }
        const float4 s = make_float4(s0, s1, s2, s3);
        const float4 x = xr[k];
        const float4 r = make_float4(x.x - s0, x.y - s1, x.z - s2, x.w - s3);
        outS4[t + 256 * k] = s;
        outR4[t + 256 * k] = r;
    }
}

extern "C" void kernel_launch(void* const* d_in, const int* in_sizes, int n_in,
                              void* d_out, int out_size, void* d_ws, size_t ws_size,
                              hipStream_t stream) {
    const float* in = (const float*)d_in[0];
    const int rows = in_sizes[0] / 4096;   // 2048
    float* seasonal = (float*)d_out;
    float* residual = seasonal + (size_t)rows * 4096;
    WaveletSeasonalDecomposer_43181601194295_kernel<<<dim3(rows), dim3(256), 0, stream>>>(
        in, seasonal, residual);
}